// Round 6
// baseline (217.075 us; speedup 1.0000x reference)
//
#include <hip/hip_runtime.h>
#include <hip/hip_bf16.h>

// TrendEncoder: histogram (B=4096, S=200 -> 256 bins) + 256-step LSTM (H=64).
// Round 11: R8's anti-phase dual-stream schedule x R10's DS-free activation.
//  Evidence through R10: co-resident waves lockstep at stall points (stable
//  attractor; R5==R10==1340cyc/step at equal per-CU issue) -> SMT hiding is
//  impossible. R8's static anti-phase was right but its act began with
//  shfl_xor (DS op) which queues behind the A-frag ds_reads in the in-order
//  lgkmcnt -> the "independent" work serialized behind the very latency it
//  was meant to cover. R10 proved the act can be 100% register-resident
//  (rows at M {0,1,4,5,8,9,12,13} -> acts on C regs r0,r1, all 64 lanes).
//  This round combines them: per phase
//    [ds_reads for stream S | act other-stream (pure reg, covers read lat)
//     | write h | counted waitcnt | mfma S (latency spans barrier) | barrier]
//  Streams: X = block rows 0-7, Y = rows 8-15; single-buffered hX/hY
//  (barrier ordering: reads of phase k complete before writes of phase k+1).
//
// Block = 16 batch rows, 256 threads (4 waves), grid 256 (1 block/CU).
// Wave wv owns gate-cols {16wv+64tt}; lane (q,m) acts units
// (stream row 2q+{0,1} = M row 4q+{0,1}, col 16wv+m) in registers.

#define B_S     200
#define B_T     256
#define ROWS    16    // 8 (X) + 8 (Y)
#define MR      16    // MFMA M dim (M rows with (R&3)>=2 are zero-pad)
#define THREADS 256
#define HS      72    // h row stride (fp16 elems) = 144 B
#define LOG2E   1.4426950408889634f

typedef __attribute__((ext_vector_type(8))) _Float16 half8;
typedef __attribute__((ext_vector_type(4))) float float4_t;
typedef __attribute__((ext_vector_type(2))) float float2_t;

__device__ __forceinline__ float load_f(const void* p, int i, int isb) {
    if (isb) {
        unsigned short u = ((const unsigned short*)p)[i];
        return __uint_as_float(((unsigned int)u) << 16);
    }
    return ((const float*)p)[i];
}

__global__ __launch_bounds__(THREADS)
void trend_encoder_kernel(const void* __restrict__ time_,
                          const int*  __restrict__ length,
                          const void* __restrict__ ptime_,
                          const void* __restrict__ wih_,
                          const void* __restrict__ whh_,
                          const void* __restrict__ bih_,
                          const void* __restrict__ bhh_,
                          void* __restrict__ out_) {
    __shared__ __align__(16) float x_t[B_T * ROWS];      // [t][row], 16 KB
    __shared__ __align__(16) _Float16 hX[MR * HS];       // X h, single buffer
    __shared__ __align__(16) _Float16 hY[MR * HS];       // Y h, single buffer
    __shared__ int flag_sh;

    const int tid  = threadIdx.x;
    const int wv   = tid >> 6;        // wave 0..3 = hidden-col tile
    const int lane = tid & 63;
    const int m    = lane & 15;
    const int quad = lane >> 4;
    const int b0   = blockIdx.x * ROWS;

    // ---- dtype probe (wave 0): W_ih ~ U(-0.125,0.125); f32 reinterpreted as
    // bf16 words goes far out of range with overwhelming probability.
    if (tid < 64) {
        unsigned short u = ((const unsigned short*)wih_)[tid];
        float v = __uint_as_float(((unsigned int)u) << 16);
        int bad = !(v > -0.2f && v < 0.2f);
        unsigned long long bm = __ballot(bad);
        if (lane == 0) flag_sh = (bm == 0ULL) ? 1 : 0;
    }
    for (int i = tid; i < B_T * ROWS; i += THREADS) x_t[i] = 0.0f;
    // zero both h buffers: pad M rows ((R&3)>=2) are never written again
    for (int i = tid; i < MR * HS; i += THREADS) hX[i] = (_Float16)0.0f;
    for (int i = tid; i < MR * HS; i += THREADS) hY[i] = (_Float16)0.0f;
    __syncthreads();
    const int isb = flag_sh;

    // ---- histogram: pos = trunc((pt - t)*0.25), add at bin 255-pos (transposed)
    for (int e = tid; e < ROWS * B_S; e += THREADS) {
        int row  = e / B_S;
        int s    = e - row * B_S;
        int grow = b0 + row;
        if (s < length[grow]) {
            float pt = load_f(ptime_, grow, isb);
            float tv = load_f(time_, grow * B_S + s, isb);
            int pos = (int)((pt - tv) * 0.25f);
            if (pos >= 0 && pos < B_T)
                atomicAdd(&x_t[(B_T - 1 - pos) * ROWS + row], 1.0f);
        }
    }

    // ---- resident weights (fp16, gate-prescaled). tile tt = gate (i,f,g,o),
    // col n = 16wv + 64tt + m.  B-frag: n = lane&15, k = 32c + 8*quad + j.
    const float gsc[4] = {-LOG2E, -LOG2E, 2.0f * LOG2E, -LOG2E};
    half8 bw[4][2];
    float wihv[4], biasv[4];
    #pragma unroll
    for (int tt = 0; tt < 4; ++tt) {
        int n = 16 * wv + 64 * tt + m;
        float s = gsc[tt];
        wihv[tt]  = load_f(wih_, n, isb) * s;
        biasv[tt] = (load_f(bih_, n, isb) + load_f(bhh_, n, isb)) * s;
        #pragma unroll
        for (int c = 0; c < 2; ++c) {
            half8 v;
            #pragma unroll
            for (int j = 0; j < 8; ++j)
                v[j] = (_Float16)(load_f(whh_, n * 64 + 32 * c + 8 * quad + j, isb) * s);
            bw[tt][c] = v;
        }
    }

    const int aoff = m * HS + 8 * quad;   // A-frag base (elems); M row m
    const int kcol = 16 * wv + m;         // owned unit column
    float cX0 = 0.f, cX1 = 0.f, cY0 = 0.f, cY1 = 0.f;
    float hXr0 = 0.f, hXr1 = 0.f, hYr0 = 0.f, hYr1 = 0.f;

    // fused in-lane activation, 100% register-resident (NO DS ops inside):
    // unit (stream batch row 2q+RR = M row 4q+RR, col kcol).
    #define ACT(CR, HR, G0, G1, G2, G3, WBP, RR)                              \
    {                                                                         \
        float A_  = __builtin_amdgcn_exp2f(G0);         /* exp2(-i*log2e) */  \
        float F_  = __builtin_amdgcn_exp2f(G1);         /* exp2(-f*log2e) */  \
        float Bv_ = __builtin_amdgcn_exp2f(G2);         /* exp2(2g*log2e) */  \
        float t1_    = (1.0f + A_) * (Bv_ + 1.0f);                            \
        float oneF_  = 1.0f + F_;                                             \
        float numer_ = fmaf(CR, t1_, oneF_ * (Bv_ - 1.0f));                   \
        float denom_ = oneF_ * t1_;                                           \
        CR = numer_ * __builtin_amdgcn_rcpf(denom_);                          \
        float D_  = __builtin_amdgcn_exp2f(G3);         /* exp2(-o*log2e) */  \
        float cs_ = fminf(CR * (2.0f * LOG2E), 126.0f); /* inf guard */       \
        float E_  = __builtin_amdgcn_exp2f(cs_);                              \
        float h_  = (E_ - 1.0f) * __builtin_amdgcn_rcpf((1.0f + D_) * (E_ + 1.0f)); \
        HR = h_;                                                              \
        WBP[(4 * quad + RR) * HS + kcol] = (_Float16)h_;                      \
    }

    #define GATES(ACC, A0, A1, XV)                                            \
    {                                                                         \
        _Pragma("unroll")                                                     \
        for (int tt = 0; tt < 4; ++tt) {                                      \
            float4_t a_;                                                      \
            a_[0] = fmaf(XV[0], wihv[tt], biasv[tt]);                         \
            a_[1] = fmaf(XV[1], wihv[tt], biasv[tt]);                         \
            a_[2] = 0.0f;   /* pad C rows: A pad rows zero -> stay 0 */       \
            a_[3] = 0.0f;                                                     \
            a_ = __builtin_amdgcn_mfma_f32_16x16x32_f16(A0, bw[tt][0], a_, 0, 0, 0); \
            a_ = __builtin_amdgcn_mfma_f32_16x16x32_f16(A1, bw[tt][1], a_, 0, 0, 0); \
            ACC[tt] = a_;                                                     \
        }                                                                     \
    }

    __syncthreads();   // histogram + h init + weights visible

    // prologue: accY = Y gates for step 0 (h_Y^0 = 0 -> no mfma term)
    float4_t accY[4];
    {
        float2_t xv0 = *(const float2_t*)&x_t[8 + 2 * quad];
        #pragma unroll
        for (int tt = 0; tt < 4; ++tt) {
            accY[tt][0] = fmaf(xv0[0], wihv[tt], biasv[tt]);
            accY[tt][1] = fmaf(xv0[1], wihv[tt], biasv[tt]);
            accY[tt][2] = 0.0f;
            accY[tt][3] = 0.0f;
        }
    }

    for (int t = 0; t < B_T; ++t) {
        // ================= phase A =================
        // issue X reads (h_X^t, published by barB(t-1)); NO wait yet
        half8 ax0 = *(const half8*)&hX[aoff];
        half8 ax1 = *(const half8*)&hX[aoff + 32];
        float2_t xvX = *(const float2_t*)&x_t[t * ROWS + 2 * quad];

        // actY: gY^(t) -> h_Y^(t+1); pure-reg trans chain covers read latency
        ACT(cY0, hYr0, accY[0][0], accY[1][0], accY[2][0], accY[3][0], hY, 0);
        ACT(cY1, hYr1, accY[0][1], accY[1][1], accY[2][1], accY[3][1], hY, 1);

        // mfmaX: gX^(t) (latency spans barA; acc consumed in phase B)
        float4_t accX[4];
        GATES(accX, ax0, ax1, xvX);
        __syncthreads();   // barA: publishes h_Y^(t+1)

        // ================= phase B =================
        half8 ay0 = *(const half8*)&hY[aoff];
        half8 ay1 = *(const half8*)&hY[aoff + 32];
        int tn = (t + 1 < B_T) ? t + 1 : t;            // t=255: dummy gates
        float2_t xvY = *(const float2_t*)&x_t[tn * ROWS + 8 + 2 * quad];

        // actX: gX^(t) -> h_X^(t+1)
        ACT(cX0, hXr0, accX[0][0], accX[1][0], accX[2][0], accX[3][0], hX, 0);
        ACT(cX1, hXr1, accX[0][1], accX[1][1], accX[2][1], accX[3][1], hX, 1);

        // mfmaY: gY^(t+1)
        GATES(accY, ay0, ay1, xvY);
        __syncthreads();   // barB: publishes h_X^(t+1)
    }
    #undef ACT
    #undef GATES

    // ---- epilogue: X rows b0+2q+{0,1}, Y rows b0+8+2q+{0,1}, col kcol
    {
        int oX = (b0 + 2 * quad) * 64 + kcol;
        int oY = (b0 + 8 + 2 * quad) * 64 + kcol;
        if (isb) {
            ((__hip_bfloat16*)out_)[oX]      = __float2bfloat16(hXr0);
            ((__hip_bfloat16*)out_)[oX + 64] = __float2bfloat16(hXr1);
            ((__hip_bfloat16*)out_)[oY]      = __float2bfloat16(hYr0);
            ((__hip_bfloat16*)out_)[oY + 64] = __float2bfloat16(hYr1);
        } else {
            ((float*)out_)[oX]      = hXr0;
            ((float*)out_)[oX + 64] = hXr1;
            ((float*)out_)[oY]      = hYr0;
            ((float*)out_)[oY + 64] = hYr1;
        }
    }
}

extern "C" void kernel_launch(void* const* d_in, const int* in_sizes, int n_in,
                              void* d_out, int out_size, void* d_ws, size_t ws_size,
                              hipStream_t stream) {
    const void* time_  = d_in[0];
    const int*  length = (const int*)d_in[1];
    const void* ptime  = d_in[2];
    const void* wih    = d_in[3];
    const void* whh    = d_in[4];
    const void* bih    = d_in[5];
    const void* bhh    = d_in[6];

    const int B = in_sizes[1];   // 4096
    trend_encoder_kernel<<<dim3(B / ROWS), dim3(THREADS), 0, stream>>>(
        time_, length, ptime, wih, whh, bih, bhh, d_out);
}

// Round 7
// 186.105 us; speedup vs baseline: 1.1664x; 1.1664x over previous
//
#include <hip/hip_runtime.h>
#include <hip/hip_bf16.h>

// TrendEncoder: histogram (B=4096, S=200 -> 256 bins) + 256-step LSTM (H=64).
// Round 12: TRANSPOSED-MFMA (operand swap) to cheapen the barrier crossing.
//  Ledger R5-R11: stall ~430-630 cyc PER BARRIER CROSSING, resists all overlap
//  (co-waves R6, cross-block R7/R10, in-wave static R8/R11). Crossings can't
//  go below 1/step (cross-wave h all-gather is fundamental). So make the
//  crossing itself cheaper: swap mfma operands -> D'[gatecol][batchrow]:
//   - A = bw (weights): SAME register data as before (W[n][k] frag).
//   - B = a0/a1 (h from LDS): SAME LDS read as before.
//   - Output: lane (q,m) holds gates for batch row m, units 16wv+4q+{0..3}
//     -> 4 ACTs/lane (trans count unchanged) producing 4 CONSECUTIVE units of
//     ONE row -> ONE ds_write_b64 replaces 4x ds_write_b16 (+2 pack).
//  Per-wave DS instrs/step: 6 -> 3 (halves the barrier-point DS burst), no
//  pad rows at all (full 16x16 MFMA efficiency), next-x prefetch issued with
//  the A-frag reads. One barrier/step, double-buffered h.
//
// Block = 16 batch rows, 256 threads (4 waves), grid 256 (1 block/CU).

#define B_S     200
#define B_T     256
#define ROWS    16
#define THREADS 256
#define HS      72    // h row stride (fp16 elems) = 144 B
#define LOG2E   1.4426950408889634f

typedef __attribute__((ext_vector_type(8))) _Float16 half8;
typedef __attribute__((ext_vector_type(4))) _Float16 half4;
typedef __attribute__((ext_vector_type(4))) float float4_t;

__device__ __forceinline__ float load_f(const void* p, int i, int isb) {
    if (isb) {
        unsigned short u = ((const unsigned short*)p)[i];
        return __uint_as_float(((unsigned int)u) << 16);
    }
    return ((const float*)p)[i];
}

__global__ __launch_bounds__(THREADS)
void trend_encoder_kernel(const void* __restrict__ time_,
                          const int*  __restrict__ length,
                          const void* __restrict__ ptime_,
                          const void* __restrict__ wih_,
                          const void* __restrict__ whh_,
                          const void* __restrict__ bih_,
                          const void* __restrict__ bhh_,
                          void* __restrict__ out_) {
    __shared__ __align__(16) float x_t[B_T * ROWS];            // [t][row], 16 KB
    __shared__ __align__(16) _Float16 h_sh[2][ROWS * HS];      // double-buffered
    __shared__ int flag_sh;

    const int tid  = threadIdx.x;
    const int wv   = tid >> 6;        // wave 0..3 = 16-unit tile
    const int lane = tid & 63;
    const int m    = lane & 15;       // batch row owned by this lane
    const int quad = lane >> 4;       // unit sub-tile: units 16wv+4q+{0..3}
    const int b0   = blockIdx.x * ROWS;

    // ---- dtype probe (wave 0): W_ih ~ U(-0.125,0.125); f32 reinterpreted as
    // bf16 words goes far out of range with overwhelming probability.
    if (tid < 64) {
        unsigned short u = ((const unsigned short*)wih_)[tid];
        float v = __uint_as_float(((unsigned int)u) << 16);
        int bad = !(v > -0.2f && v < 0.2f);
        unsigned long long bm = __ballot(bad);
        if (lane == 0) flag_sh = (bm == 0ULL) ? 1 : 0;
    }
    for (int i = tid; i < B_T * ROWS; i += THREADS) x_t[i] = 0.0f;
    {   // zero both h buffers (h^0 = 0; every step fully overwrites its buffer)
        _Float16* hz = &h_sh[0][0];
        for (int i = tid; i < 2 * ROWS * HS; i += THREADS) hz[i] = (_Float16)0.0f;
    }
    __syncthreads();
    const int isb = flag_sh;

    // ---- histogram: pos = trunc((pt - t)*0.25), add at bin 255-pos (transposed)
    for (int e = tid; e < ROWS * B_S; e += THREADS) {
        int row  = e / B_S;
        int s    = e - row * B_S;
        int grow = b0 + row;
        if (s < length[grow]) {
            float pt = load_f(ptime_, grow, isb);
            float tv = load_f(time_, grow * B_S + s, isb);
            int pos = (int)((pt - tv) * 0.25f);
            if (pos >= 0 && pos < B_T)
                atomicAdd(&x_t[(B_T - 1 - pos) * ROWS + row], 1.0f);
        }
    }

    // ---- resident weights (fp16, gate-prescaled), same frag data as before,
    // now used as the A operand. tt = gate (i,f,g,o); A[i=m][k=32c+8q+j] =
    // W[16wv+64tt+i][k]*gsc.
    const float gsc[4] = {-LOG2E, -LOG2E, 2.0f * LOG2E, -LOG2E};
    half8 bw[4][2];
    float wihv[4][4], biasv[4][4];    // [tt][r]: per-lane unit 16wv+4q+r
    #pragma unroll
    for (int tt = 0; tt < 4; ++tt) {
        float s = gsc[tt];
        {
            int n = 16 * wv + 64 * tt + m;
            #pragma unroll
            for (int c = 0; c < 2; ++c) {
                half8 v;
                #pragma unroll
                for (int j = 0; j < 8; ++j)
                    v[j] = (_Float16)(load_f(whh_, n * 64 + 32 * c + 8 * quad + j, isb) * s);
                bw[tt][c] = v;
            }
        }
        #pragma unroll
        for (int r = 0; r < 4; ++r) {
            int n = 64 * tt + 16 * wv + 4 * quad + r;
            wihv[tt][r]  = load_f(wih_, n, isb) * s;
            biasv[tt][r] = (load_f(bih_, n, isb) + load_f(bhh_, n, isb)) * s;
        }
    }

    const int aoff = m * HS + 8 * quad;            // h read: row m, k=8q..8q+7
    const int woff = m * HS + 16 * wv + 4 * quad;  // h write: row m, 4 units, b64
    float c0 = 0.f, c1 = 0.f, c2 = 0.f, c3 = 0.f;
    float h0 = 0.f, h1 = 0.f, h2 = 0.f, h3 = 0.f;
    __syncthreads();   // histogram + h init + weights visible

    // fused in-lane activation for unit 16wv+4q+R, batch row m
    #define ACT(CR, HR, G0, G1, G2, G3)                                       \
    {                                                                         \
        float A_  = __builtin_amdgcn_exp2f(G0);         /* exp2(-i*log2e) */  \
        float F_  = __builtin_amdgcn_exp2f(G1);         /* exp2(-f*log2e) */  \
        float Bv_ = __builtin_amdgcn_exp2f(G2);         /* exp2(2g*log2e) */  \
        float t1_    = (1.0f + A_) * (Bv_ + 1.0f);                            \
        float oneF_  = 1.0f + F_;                                             \
        float numer_ = fmaf(CR, t1_, oneF_ * (Bv_ - 1.0f));                   \
        float denom_ = oneF_ * t1_;                                           \
        CR = numer_ * __builtin_amdgcn_rcpf(denom_);                          \
        float D_  = __builtin_amdgcn_exp2f(G3);         /* exp2(-o*log2e) */  \
        float cs_ = fminf(CR * (2.0f * LOG2E), 126.0f); /* inf guard */       \
        float E_  = __builtin_amdgcn_exp2f(cs_);                              \
        HR = (E_ - 1.0f) * __builtin_amdgcn_rcpf((1.0f + D_) * (E_ + 1.0f));  \
    }

    float xb = x_t[m];   // x[t=0] for row m

    for (int t = 0; t < B_T; ++t) {
        const int p = t & 1;
        const _Float16* hh = h_sh[p];
        // B fragments: h^t row m, k-slices (same read pattern as before)
        half8 a0 = *(const half8*)&hh[aoff];
        half8 a1 = *(const half8*)&hh[aoff + 32];
        // prefetch next x (static data; queues with the reads, used next step)
        int tn = (t + 1 < B_T) ? t + 1 : t;
        float nxb = x_t[tn * ROWS + m];

        // gates D'[unit-local 4q+r][row m]: acc[tt][r]
        float4_t acc[4];
        #pragma unroll
        for (int tt = 0; tt < 4; ++tt) {
            float4_t a;
            #pragma unroll
            for (int r = 0; r < 4; ++r) a[r] = fmaf(xb, wihv[tt][r], biasv[tt][r]);
            a = __builtin_amdgcn_mfma_f32_16x16x32_f16(bw[tt][0], a0, a, 0, 0, 0);
            a = __builtin_amdgcn_mfma_f32_16x16x32_f16(bw[tt][1], a1, a, 0, 0, 0);
            acc[tt] = a;
        }

        // activation: 4 units of row m, all in-lane, all lanes live
        ACT(c0, h0, acc[0][0], acc[1][0], acc[2][0], acc[3][0]);
        ACT(c1, h1, acc[0][1], acc[1][1], acc[2][1], acc[3][1]);
        ACT(c2, h2, acc[0][2], acc[1][2], acc[2][2], acc[3][2]);
        ACT(c3, h3, acc[0][3], acc[1][3], acc[2][3], acc[3][3]);

        // ONE vectorized h write: 4 consecutive units of row m (b64)
        half4 hv;
        hv[0] = (_Float16)h0; hv[1] = (_Float16)h1;
        hv[2] = (_Float16)h2; hv[3] = (_Float16)h3;
        *(half4*)&h_sh[p ^ 1][woff] = hv;

        xb = nxb;
        __syncthreads();   // the only barrier per step
    }
    #undef ACT

    // ---- epilogue: row b0+m, units 16wv+4q+{0..3}
    {
        int ob = (b0 + m) * 64 + 16 * wv + 4 * quad;
        if (isb) {
            ((__hip_bfloat16*)out_)[ob + 0] = __float2bfloat16(h0);
            ((__hip_bfloat16*)out_)[ob + 1] = __float2bfloat16(h1);
            ((__hip_bfloat16*)out_)[ob + 2] = __float2bfloat16(h2);
            ((__hip_bfloat16*)out_)[ob + 3] = __float2bfloat16(h3);
        } else {
            ((float*)out_)[ob + 0] = h0;
            ((float*)out_)[ob + 1] = h1;
            ((float*)out_)[ob + 2] = h2;
            ((float*)out_)[ob + 3] = h3;
        }
    }
}

extern "C" void kernel_launch(void* const* d_in, const int* in_sizes, int n_in,
                              void* d_out, int out_size, void* d_ws, size_t ws_size,
                              hipStream_t stream) {
    const void* time_  = d_in[0];
    const int*  length = (const int*)d_in[1];
    const void* ptime  = d_in[2];
    const void* wih    = d_in[3];
    const void* whh    = d_in[4];
    const void* bih    = d_in[5];
    const void* bhh    = d_in[6];

    const int B = in_sizes[1];   // 4096
    trend_encoder_kernel<<<dim3(B / ROWS), dim3(THREADS), 0, stream>>>(
        time_, length, ptime, wih, whh, bih, bhh, d_out);
}

// Round 8
// 179.269 us; speedup vs baseline: 1.2109x; 1.0381x over previous
//
#include <hip/hip_runtime.h>
#include <hip/hip_bf16.h>

// TrendEncoder: histogram (B=4096, S=200 -> 256 bins) + 256-step LSTM (H=64).
// Round 13: R12 (transposed-MFMA, 1 barrier/step) + serial-chain trims.
//  Model after R12: step = serial chain (barrier -> ds_read h -> 2 MFMA ->
//  act trans chain -> pack/write -> barrier) ~= 1284 cyc; issue is embedded
//  in the chain, co-scheduling can't fill it (R6-R11), barrier-free loses to
//  MFMA duplication (R9). So: shave the chain.
//   (a) x re-laid as [row][t] f32 (padded stride 260): one float4 ds_read per
//       4 steps, prefetched a group ahead; inner 4-step loop unrolled so all
//       vector indices and buffer parity (k&1) are compile-time. Removes a
//       dependent ds_read_b32 + ~5 VALU (tn branch) per step.
//   (b) histogram time loads vectorized 4-wide (float4 / ushort4) -> 3.2
//       latency-bound iterations instead of 12.5 in the prologue.
//  Everything else identical to R12 (verified): transposed MFMA (A=weights,
//  B=h), lane (q,m) acts units 16wv+4q+{0..3} of batch row m, one b64 h
//  write, double-buffered h, 1 block/CU.
//
// Block = 16 batch rows, 256 threads (4 waves), grid 256 (1 block/CU).

#define B_S     200
#define B_T     256
#define ROWS    16
#define THREADS 256
#define HS      72    // h row stride (fp16 elems) = 144 B
#define XS      260   // x row stride (f32): 256 + 4 pad (prefetch overrun)
#define LOG2E   1.4426950408889634f

typedef __attribute__((ext_vector_type(8))) _Float16 half8;
typedef __attribute__((ext_vector_type(4))) _Float16 half4;
typedef __attribute__((ext_vector_type(4))) float float4_t;
typedef __attribute__((ext_vector_type(4))) unsigned short ushort4_t;

__device__ __forceinline__ float load_f(const void* p, int i, int isb) {
    if (isb) {
        unsigned short u = ((const unsigned short*)p)[i];
        return __uint_as_float(((unsigned int)u) << 16);
    }
    return ((const float*)p)[i];
}

__global__ __launch_bounds__(THREADS)
void trend_encoder_kernel(const void* __restrict__ time_,
                          const int*  __restrict__ length,
                          const void* __restrict__ ptime_,
                          const void* __restrict__ wih_,
                          const void* __restrict__ whh_,
                          const void* __restrict__ bih_,
                          const void* __restrict__ bhh_,
                          void* __restrict__ out_) {
    __shared__ __align__(16) float x32[ROWS * XS];             // [row][t], 16.6 KB
    __shared__ __align__(16) _Float16 h_sh[2][ROWS * HS];      // double-buffered
    __shared__ int flag_sh;

    const int tid  = threadIdx.x;
    const int wv   = tid >> 6;        // wave 0..3 = 16-unit tile
    const int lane = tid & 63;
    const int m    = lane & 15;       // batch row owned by this lane
    const int quad = lane >> 4;       // unit sub-tile: units 16wv+4q+{0..3}
    const int b0   = blockIdx.x * ROWS;

    // ---- dtype probe (wave 0): W_ih ~ U(-0.125,0.125); f32 reinterpreted as
    // bf16 words goes far out of range with overwhelming probability.
    if (tid < 64) {
        unsigned short u = ((const unsigned short*)wih_)[tid];
        float v = __uint_as_float(((unsigned int)u) << 16);
        int bad = !(v > -0.2f && v < 0.2f);
        unsigned long long bm = __ballot(bad);
        if (lane == 0) flag_sh = (bm == 0ULL) ? 1 : 0;
    }
    for (int i = tid; i < ROWS * XS; i += THREADS) x32[i] = 0.0f;
    {   // zero both h buffers (h^0 = 0; every step fully overwrites its buffer)
        _Float16* hz = &h_sh[0][0];
        for (int i = tid; i < 2 * ROWS * HS; i += THREADS) hz[i] = (_Float16)0.0f;
    }
    __syncthreads();
    const int isb = flag_sh;

    // ---- histogram: pos = trunc((pt - t)*0.25), add at bin 255-pos.
    // 4-wide vectorized time loads (alignment: 200 and s4 are mult of 4).
    for (int e = tid; e < ROWS * (B_S / 4); e += THREADS) {
        int row  = e / (B_S / 4);
        int s4   = (e - row * (B_S / 4)) * 4;
        int grow = b0 + row;
        int len  = length[grow];
        float pt = load_f(ptime_, grow, isb);
        float tv[4];
        if (isb) {
            ushort4_t u = *(const ushort4_t*)((const unsigned short*)time_ +
                                              grow * B_S + s4);
            #pragma unroll
            for (int j = 0; j < 4; ++j)
                tv[j] = __uint_as_float(((unsigned int)u[j]) << 16);
        } else {
            float4_t v = *(const float4_t*)((const float*)time_ + grow * B_S + s4);
            #pragma unroll
            for (int j = 0; j < 4; ++j) tv[j] = v[j];
        }
        #pragma unroll
        for (int j = 0; j < 4; ++j) {
            if (s4 + j < len) {
                int pos = (int)((pt - tv[j]) * 0.25f);
                if (pos >= 0 && pos < B_T)
                    atomicAdd(&x32[row * XS + (B_T - 1 - pos)], 1.0f);
            }
        }
    }

    // ---- resident weights (fp16, gate-prescaled), A operand of the
    // transposed MFMA. tt = gate (i,f,g,o); A[i=m][k=32c+8q+j] =
    // W[16wv+64tt+i][k]*gsc.
    const float gsc[4] = {-LOG2E, -LOG2E, 2.0f * LOG2E, -LOG2E};
    half8 bw[4][2];
    float wihv[4][4], biasv[4][4];    // [tt][r]: per-lane unit 16wv+4q+r
    #pragma unroll
    for (int tt = 0; tt < 4; ++tt) {
        float s = gsc[tt];
        {
            int n = 16 * wv + 64 * tt + m;
            #pragma unroll
            for (int c = 0; c < 2; ++c) {
                half8 v;
                #pragma unroll
                for (int j = 0; j < 8; ++j)
                    v[j] = (_Float16)(load_f(whh_, n * 64 + 32 * c + 8 * quad + j, isb) * s);
                bw[tt][c] = v;
            }
        }
        #pragma unroll
        for (int r = 0; r < 4; ++r) {
            int n = 64 * tt + 16 * wv + 4 * quad + r;
            wihv[tt][r]  = load_f(wih_, n, isb) * s;
            biasv[tt][r] = (load_f(bih_, n, isb) + load_f(bhh_, n, isb)) * s;
        }
    }

    const int aoff = m * HS + 8 * quad;            // h read: row m, k=8q..8q+7
    const int woff = m * HS + 16 * wv + 4 * quad;  // h write: row m, 4 units, b64
    float c0 = 0.f, c1 = 0.f, c2 = 0.f, c3 = 0.f;
    float h0 = 0.f, h1 = 0.f, h2 = 0.f, h3 = 0.f;
    __syncthreads();   // histogram + h init + weights visible

    // fused in-lane activation for unit 16wv+4q+R, batch row m
    #define ACT(CR, HR, G0, G1, G2, G3)                                       \
    {                                                                         \
        float A_  = __builtin_amdgcn_exp2f(G0);         /* exp2(-i*log2e) */  \
        float F_  = __builtin_amdgcn_exp2f(G1);         /* exp2(-f*log2e) */  \
        float Bv_ = __builtin_amdgcn_exp2f(G2);         /* exp2(2g*log2e) */  \
        float t1_    = (1.0f + A_) * (Bv_ + 1.0f);                            \
        float oneF_  = 1.0f + F_;                                             \
        float numer_ = fmaf(CR, t1_, oneF_ * (Bv_ - 1.0f));                   \
        float denom_ = oneF_ * t1_;                                           \
        CR = numer_ * __builtin_amdgcn_rcpf(denom_);                          \
        float D_  = __builtin_amdgcn_exp2f(G3);         /* exp2(-o*log2e) */  \
        float cs_ = fminf(CR * (2.0f * LOG2E), 126.0f); /* inf guard */       \
        float E_  = __builtin_amdgcn_exp2f(cs_);                              \
        HR = (E_ - 1.0f) * __builtin_amdgcn_rcpf((1.0f + D_) * (E_ + 1.0f));  \
    }

    // x stream: lane reads its row's 4-step group, prefetched one group ahead
    float4_t xq = *(const float4_t*)&x32[m * XS];   // steps 0..3

    for (int t8 = 0; t8 < B_T; t8 += 4) {
        // prefetch next 4-step group (pad cols 256..259 are zero; harmless)
        float4_t xqn = *(const float4_t*)&x32[m * XS + t8 + 4];

        #pragma unroll
        for (int k = 0; k < 4; ++k) {
            // t = t8 + k; buffer parity (t&1) == (k&1): compile-time
            const _Float16* hh = h_sh[k & 1];
            // B fragments: h^t row m, k-slices (first thing post-barrier)
            half8 a0 = *(const half8*)&hh[aoff];
            half8 a1 = *(const half8*)&hh[aoff + 32];
            float xb = xq[k];   // static index (unrolled)

            // gates D'[unit-local 4q+r][row m]: acc[tt][r]
            float4_t acc[4];
            #pragma unroll
            for (int tt = 0; tt < 4; ++tt) {
                float4_t a;
                #pragma unroll
                for (int r = 0; r < 4; ++r)
                    a[r] = fmaf(xb, wihv[tt][r], biasv[tt][r]);
                a = __builtin_amdgcn_mfma_f32_16x16x32_f16(bw[tt][0], a0, a, 0, 0, 0);
                a = __builtin_amdgcn_mfma_f32_16x16x32_f16(bw[tt][1], a1, a, 0, 0, 0);
                acc[tt] = a;
            }

            // activation: 4 units of row m, all in-lane, all lanes live
            ACT(c0, h0, acc[0][0], acc[1][0], acc[2][0], acc[3][0]);
            ACT(c1, h1, acc[0][1], acc[1][1], acc[2][1], acc[3][1]);
            ACT(c2, h2, acc[0][2], acc[1][2], acc[2][2], acc[3][2]);
            ACT(c3, h3, acc[0][3], acc[1][3], acc[2][3], acc[3][3]);

            // ONE vectorized h write: 4 consecutive units of row m (b64)
            half4 hv;
            hv[0] = (_Float16)h0; hv[1] = (_Float16)h1;
            hv[2] = (_Float16)h2; hv[3] = (_Float16)h3;
            *(half4*)&h_sh[(k & 1) ^ 1][woff] = hv;

            __syncthreads();   // the only barrier per step
        }
        xq = xqn;
    }
    #undef ACT

    // ---- epilogue: row b0+m, units 16wv+4q+{0..3}
    {
        int ob = (b0 + m) * 64 + 16 * wv + 4 * quad;
        if (isb) {
            ((__hip_bfloat16*)out_)[ob + 0] = __float2bfloat16(h0);
            ((__hip_bfloat16*)out_)[ob + 1] = __float2bfloat16(h1);
            ((__hip_bfloat16*)out_)[ob + 2] = __float2bfloat16(h2);
            ((__hip_bfloat16*)out_)[ob + 3] = __float2bfloat16(h3);
        } else {
            ((float*)out_)[ob + 0] = h0;
            ((float*)out_)[ob + 1] = h1;
            ((float*)out_)[ob + 2] = h2;
            ((float*)out_)[ob + 3] = h3;
        }
    }
}

extern "C" void kernel_launch(void* const* d_in, const int* in_sizes, int n_in,
                              void* d_out, int out_size, void* d_ws, size_t ws_size,
                              hipStream_t stream) {
    const void* time_  = d_in[0];
    const int*  length = (const int*)d_in[1];
    const void* ptime  = d_in[2];
    const void* wih    = d_in[3];
    const void* whh    = d_in[4];
    const void* bih    = d_in[5];
    const void* bhh    = d_in[6];

    const int B = in_sizes[1];   // 4096
    trend_encoder_kernel<<<dim3(B / ROWS), dim3(THREADS), 0, stream>>>(
        time_, length, ptime, wih, whh, bih, bhh, d_out);
}

// Round 9
// 174.468 us; speedup vs baseline: 1.2442x; 1.0275x over previous
//
#include <hip/hip_runtime.h>
#include <hip/hip_bf16.h>

// TrendEncoder: histogram (B=4096, S=200 -> 256 bins) + 256-step LSTM (H=64).
// Round 14: prologue trims only; loop body frozen (R13, validated).
//  Model (validated to <1%): step = 605 issue (trans floor: 28 wave-trans
//  x 16cyc; 7 trans/unit is algebraically minimal) + 582 chain latency
//  (read 120 + MFMA dep + act tail + drain + barrier). Five overlap schemes
//  failed to dent the 582 (R6-R11); 2 trim rounds matched predictions.
//  Remaining fat is the FIXED PROLOGUE (~4-6us of 126.6):
//   (a) weights vectorized (ushort8 / 2x float4; wih/bias 4-wide) and issued
//       BEFORE the histogram so both global-latency rounds overlap.
//   (b) histogram re-indexed 16-threads-per-row: length/ptime loaded once
//       per thread, <=4 vector time loads, no div/mod.
//   (c) float4 LDS zero-fill; vectorized epilogue store (b64 bf16/b128 f32).
//
// Block = 16 batch rows, 256 threads (4 waves), grid 256 (1 block/CU).
// Transposed MFMA (A=weights, B=h): lane (q,m) acts units 16wv+4q+{0..3} of
// batch row m; one b64 h write; double-buffered h; 1 barrier/step.

#define B_S     200
#define B_T     256
#define ROWS    16
#define THREADS 256
#define HS      72    // h row stride (fp16 elems) = 144 B
#define XS      260   // x row stride (f32): 256 + 4 pad (prefetch overrun)
#define LOG2E   1.4426950408889634f

typedef __attribute__((ext_vector_type(8))) _Float16 half8;
typedef __attribute__((ext_vector_type(4))) _Float16 half4;
typedef __attribute__((ext_vector_type(4))) float float4_t;
typedef __attribute__((ext_vector_type(4))) unsigned short ushort4_t;
typedef __attribute__((ext_vector_type(8))) unsigned short ushort8_t;

__device__ __forceinline__ float load_f(const void* p, int i, int isb) {
    if (isb) {
        unsigned short u = ((const unsigned short*)p)[i];
        return __uint_as_float(((unsigned int)u) << 16);
    }
    return ((const float*)p)[i];
}

__device__ __forceinline__ float b2f(unsigned short u) {
    return __uint_as_float(((unsigned int)u) << 16);
}

__global__ __launch_bounds__(THREADS)
void trend_encoder_kernel(const void* __restrict__ time_,
                          const int*  __restrict__ length,
                          const void* __restrict__ ptime_,
                          const void* __restrict__ wih_,
                          const void* __restrict__ whh_,
                          const void* __restrict__ bih_,
                          const void* __restrict__ bhh_,
                          void* __restrict__ out_) {
    __shared__ __align__(16) float x32[ROWS * XS];             // [row][t], 16.6 KB
    __shared__ __align__(16) _Float16 h_sh[2][ROWS * HS];      // double-buffered
    __shared__ int flag_sh;

    const int tid  = threadIdx.x;
    const int wv   = tid >> 6;        // wave 0..3 = 16-unit tile
    const int lane = tid & 63;
    const int m    = lane & 15;       // batch row owned by this lane
    const int quad = lane >> 4;       // unit sub-tile: units 16wv+4q+{0..3}
    const int b0   = blockIdx.x * ROWS;

    // ---- dtype probe (wave 0): W_ih ~ U(-0.125,0.125); f32 reinterpreted as
    // bf16 words goes far out of range with overwhelming probability.
    if (tid < 64) {
        unsigned short u = ((const unsigned short*)wih_)[tid];
        float v = b2f(u);
        int bad = !(v > -0.2f && v < 0.2f);
        unsigned long long bm = __ballot(bad);
        if (lane == 0) flag_sh = (bm == 0ULL) ? 1 : 0;
    }
    // vectorized LDS zero-fill (x32: 4160 f32 = 1040 float4; h: 4608B = 288)
    {
        float4_t z = (float4_t)0.0f;
        float4_t* xz = (float4_t*)x32;
        for (int i = tid; i < (ROWS * XS) / 4; i += THREADS) xz[i] = z;
        float4_t* hz = (float4_t*)&h_sh[0][0];
        for (int i = tid; i < (2 * ROWS * HS) / 8; i += THREADS) hz[i] = z;
    }
    __syncthreads();
    const int isb = flag_sh;

    // ---- resident weights FIRST (their global-load latency overlaps the
    // histogram's loads below). Transposed-MFMA A operand; tt = gate
    // (i,f,g,o); A[i=m][k=32c+8q+j] = W[16wv+64tt+i][k]*gsc.
    const float gsc[4] = {-LOG2E, -LOG2E, 2.0f * LOG2E, -LOG2E};
    half8 bw[4][2];
    float wihv[4][4], biasv[4][4];    // [tt][r]: per-lane unit 16wv+4q+r
    #pragma unroll
    for (int tt = 0; tt < 4; ++tt) {
        float s = gsc[tt];
        int n = 16 * wv + 64 * tt + m;
        #pragma unroll
        for (int c = 0; c < 2; ++c) {
            half8 v;
            int off = n * 64 + 32 * c + 8 * quad;
            if (isb) {
                ushort8_t u = *(const ushort8_t*)((const unsigned short*)whh_ + off);
                #pragma unroll
                for (int j = 0; j < 8; ++j) v[j] = (_Float16)(b2f(u[j]) * s);
            } else {
                float4_t f0 = *(const float4_t*)((const float*)whh_ + off);
                float4_t f1 = *(const float4_t*)((const float*)whh_ + off + 4);
                #pragma unroll
                for (int j = 0; j < 4; ++j) {
                    v[j]     = (_Float16)(f0[j] * s);
                    v[j + 4] = (_Float16)(f1[j] * s);
                }
            }
            bw[tt][c] = v;
        }
        int n0 = 64 * tt + 16 * wv + 4 * quad;
        if (isb) {
            ushort4_t uw = *(const ushort4_t*)((const unsigned short*)wih_ + n0);
            ushort4_t u1 = *(const ushort4_t*)((const unsigned short*)bih_ + n0);
            ushort4_t u2 = *(const ushort4_t*)((const unsigned short*)bhh_ + n0);
            #pragma unroll
            for (int r = 0; r < 4; ++r) {
                wihv[tt][r]  = b2f(uw[r]) * s;
                biasv[tt][r] = (b2f(u1[r]) + b2f(u2[r])) * s;
            }
        } else {
            float4_t fw = *(const float4_t*)((const float*)wih_ + n0);
            float4_t f1 = *(const float4_t*)((const float*)bih_ + n0);
            float4_t f2 = *(const float4_t*)((const float*)bhh_ + n0);
            #pragma unroll
            for (int r = 0; r < 4; ++r) {
                wihv[tt][r]  = fw[r] * s;
                biasv[tt][r] = (f1[r] + f2[r]) * s;
            }
        }
    }

    // ---- histogram: pos = trunc((pt - t)*0.25), add at bin 255-pos.
    // 16 threads per row; length/ptime loaded once; <=4 vector time loads.
    {
        const int row  = tid >> 4;
        const int tpos = tid & 15;
        const int grow = b0 + row;
        const int len  = length[grow];
        const float pt = load_f(ptime_, grow, isb);
        #pragma unroll
        for (int k = 0; k < 4; ++k) {
            int s4 = tpos * 4 + k * 64;
            if (s4 < B_S) {
                float tv[4];
                if (isb) {
                    ushort4_t u = *(const ushort4_t*)((const unsigned short*)time_ +
                                                      grow * B_S + s4);
                    #pragma unroll
                    for (int j = 0; j < 4; ++j) tv[j] = b2f(u[j]);
                } else {
                    float4_t v = *(const float4_t*)((const float*)time_ +
                                                    grow * B_S + s4);
                    #pragma unroll
                    for (int j = 0; j < 4; ++j) tv[j] = v[j];
                }
                #pragma unroll
                for (int j = 0; j < 4; ++j) {
                    if (s4 + j < len) {
                        int pos = (int)((pt - tv[j]) * 0.25f);
                        if (pos >= 0 && pos < B_T)
                            atomicAdd(&x32[row * XS + (B_T - 1 - pos)], 1.0f);
                    }
                }
            }
        }
    }

    const int aoff = m * HS + 8 * quad;            // h read: row m, k=8q..8q+7
    const int woff = m * HS + 16 * wv + 4 * quad;  // h write: row m, 4 units, b64
    float c0 = 0.f, c1 = 0.f, c2 = 0.f, c3 = 0.f;
    float h0 = 0.f, h1 = 0.f, h2 = 0.f, h3 = 0.f;
    __syncthreads();   // histogram + h init visible

    // fused in-lane activation for unit 16wv+4q+R, batch row m
    #define ACT(CR, HR, G0, G1, G2, G3)                                       \
    {                                                                         \
        float A_  = __builtin_amdgcn_exp2f(G0);         /* exp2(-i*log2e) */  \
        float F_  = __builtin_amdgcn_exp2f(G1);         /* exp2(-f*log2e) */  \
        float Bv_ = __builtin_amdgcn_exp2f(G2);         /* exp2(2g*log2e) */  \
        float t1_    = (1.0f + A_) * (Bv_ + 1.0f);                            \
        float oneF_  = 1.0f + F_;                                             \
        float numer_ = fmaf(CR, t1_, oneF_ * (Bv_ - 1.0f));                   \
        float denom_ = oneF_ * t1_;                                           \
        CR = numer_ * __builtin_amdgcn_rcpf(denom_);                          \
        float D_  = __builtin_amdgcn_exp2f(G3);         /* exp2(-o*log2e) */  \
        float cs_ = fminf(CR * (2.0f * LOG2E), 126.0f); /* inf guard */       \
        float E_  = __builtin_amdgcn_exp2f(cs_);                              \
        HR = (E_ - 1.0f) * __builtin_amdgcn_rcpf((1.0f + D_) * (E_ + 1.0f));  \
    }

    // x stream: lane reads its row's 4-step group, prefetched one group ahead
    float4_t xq = *(const float4_t*)&x32[m * XS];   // steps 0..3

    for (int t8 = 0; t8 < B_T; t8 += 4) {
        // prefetch next 4-step group (pad cols 256..259 are zero; harmless)
        float4_t xqn = *(const float4_t*)&x32[m * XS + t8 + 4];

        #pragma unroll
        for (int k = 0; k < 4; ++k) {
            // t = t8 + k; buffer parity (t&1) == (k&1): compile-time
            const _Float16* hh = h_sh[k & 1];
            // B fragments: h^t row m, k-slices (first thing post-barrier)
            half8 a0 = *(const half8*)&hh[aoff];
            half8 a1 = *(const half8*)&hh[aoff + 32];
            float xb = xq[k];   // static index (unrolled)

            // gates D'[unit-local 4q+r][row m]: acc[tt][r]
            float4_t acc[4];
            #pragma unroll
            for (int tt = 0; tt < 4; ++tt) {
                float4_t a;
                #pragma unroll
                for (int r = 0; r < 4; ++r)
                    a[r] = fmaf(xb, wihv[tt][r], biasv[tt][r]);
                a = __builtin_amdgcn_mfma_f32_16x16x32_f16(bw[tt][0], a0, a, 0, 0, 0);
                a = __builtin_amdgcn_mfma_f32_16x16x32_f16(bw[tt][1], a1, a, 0, 0, 0);
                acc[tt] = a;
            }

            // activation: 4 units of row m, all in-lane, all lanes live
            ACT(c0, h0, acc[0][0], acc[1][0], acc[2][0], acc[3][0]);
            ACT(c1, h1, acc[0][1], acc[1][1], acc[2][1], acc[3][1]);
            ACT(c2, h2, acc[0][2], acc[1][2], acc[2][2], acc[3][2]);
            ACT(c3, h3, acc[0][3], acc[1][3], acc[2][3], acc[3][3]);

            // ONE vectorized h write: 4 consecutive units of row m (b64)
            half4 hv;
            hv[0] = (_Float16)h0; hv[1] = (_Float16)h1;
            hv[2] = (_Float16)h2; hv[3] = (_Float16)h3;
            *(half4*)&h_sh[(k & 1) ^ 1][woff] = hv;

            __syncthreads();   // the only barrier per step
        }
        xq = xqn;
    }
    #undef ACT

    // ---- epilogue: row b0+m, units 16wv+4q+{0..3} (vectorized store)
    {
        int ob = (b0 + m) * 64 + 16 * wv + 4 * quad;
        if (isb) {
            ushort4_t o4;
            __hip_bfloat16 t0 = __float2bfloat16(h0);
            __hip_bfloat16 t1 = __float2bfloat16(h1);
            __hip_bfloat16 t2 = __float2bfloat16(h2);
            __hip_bfloat16 t3 = __float2bfloat16(h3);
            o4[0] = *(unsigned short*)&t0;
            o4[1] = *(unsigned short*)&t1;
            o4[2] = *(unsigned short*)&t2;
            o4[3] = *(unsigned short*)&t3;
            *(ushort4_t*)((unsigned short*)out_ + ob) = o4;   // 8B store
        } else {
            float4_t fo;
            fo[0] = h0; fo[1] = h1; fo[2] = h2; fo[3] = h3;
            *(float4_t*)((float*)out_ + ob) = fo;             // 16B store
        }
    }
}

extern "C" void kernel_launch(void* const* d_in, const int* in_sizes, int n_in,
                              void* d_out, int out_size, void* d_ws, size_t ws_size,
                              hipStream_t stream) {
    const void* time_  = d_in[0];
    const int*  length = (const int*)d_in[1];
    const void* ptime  = d_in[2];
    const void* wih    = d_in[3];
    const void* whh    = d_in[4];
    const void* bih    = d_in[5];
    const void* bhh    = d_in[6];

    const int B = in_sizes[1];   // 4096
    trend_encoder_kernel<<<dim3(B / ROWS), dim3(THREADS), 0, stream>>>(
        time_, length, ptime, wih, whh, bih, bhh, d_out);
}